// Round 3
// baseline (89.601 us; speedup 1.0000x reference)
//
#include <hip/hip_runtime.h>
#include <hip/hip_bf16.h>
#include <math.h>

#define B_DIM 16
#define T_DIM 100
#define TPAD 112            // X16 rows per batch (12 zeroed pad rows)
#define HW_PIX (27 * 48)    // 1296 pixels/frame
#define NBINS 512
#define WIN 101
#define HALF 50
#define ODIM 128
#define NCHUNK 7            // t-chunks of 16 per batch
#define SSTR 132            // slds col stride (128 + 4 pad)

typedef __attribute__((ext_vector_type(8))) short s16x8;
typedef __attribute__((ext_vector_type(4))) float f32x4;

// ---------------------------------------------------------------------------
// Kernel A: per-frame 512-bin histogram, L2-normalized, stored bf16 into
// X16[b][tpad][512] with rows 100..111 zeroed (MFMA padding).
// blocks 0..1599: one frame each. blocks 1600..1791: zero one pad row each.
// ---------------------------------------------------------------------------
__global__ __launch_bounds__(256) void hist_kernel(
    const int* __restrict__ frames, __hip_bfloat16* __restrict__ X16) {
  const int bid = blockIdx.x;
  const int tid = threadIdx.x;

  if (bid >= B_DIM * T_DIM) {
    const int pid = bid - B_DIM * T_DIM;      // 0..191
    const int b = pid / (TPAD - T_DIM);
    const int r = pid - b * (TPAD - T_DIM);
    unsigned int* row = (unsigned int*)(X16 + ((size_t)(b * TPAD + T_DIM + r)) * NBINS);
    row[tid] = 0u;                             // 256 uints = 512 bf16
    return;
  }

  __shared__ int h[NBINS];
  __shared__ float red[16];

  for (int i = tid; i < NBINS; i += 256) h[i] = 0;
  __syncthreads();

  // 1296 pixels = 324 groups of 4 pixels (12 dwords = 3 int4 loads)
  const int* fp = frames + (size_t)bid * (HW_PIX * 3);
  for (int i = tid; i < HW_PIX / 4; i += 256) {
    const int4* q = (const int4*)(fp + 12 * i);
    int4 a = q[0], c = q[1], e = q[2];
    int b0 = ((a.x >> 5) << 6) + ((a.y >> 5) << 3) + (a.z >> 5);
    int b1 = ((a.w >> 5) << 6) + ((c.x >> 5) << 3) + (c.y >> 5);
    int b2 = ((c.z >> 5) << 6) + ((c.w >> 5) << 3) + (e.x >> 5);
    int b3 = ((e.y >> 5) << 6) + ((e.z >> 5) << 3) + (e.w >> 5);
    atomicAdd(&h[b0], 1);
    atomicAdd(&h[b1], 1);
    atomicAdd(&h[b2], 1);
    atomicAdd(&h[b3], 1);
  }
  __syncthreads();

  float ss = 0.f;
  for (int i = tid; i < NBINS; i += 256) {
    float v = (float)h[i];
    ss += v * v;
  }
  const int lane = tid & 63, wave = tid >> 6;
#pragma unroll
  for (int off = 32; off > 0; off >>= 1) ss += __shfl_down(ss, off);
  if (lane == 0) red[wave] = ss;
  __syncthreads();
  if (tid == 0) red[8] = 1.0f / sqrtf(red[0] + red[1] + red[2] + red[3]);
  __syncthreads();
  const float rn = red[8];

  const int b = bid / T_DIM;
  const int t = bid - b * T_DIM;
  __hip_bfloat16* row = X16 + ((size_t)(b * TPAD + t)) * NBINS;
  for (int i = tid; i < NBINS; i += 256) row[i] = __float2bfloat16((float)h[i] * rn);
}

// ---------------------------------------------------------------------------
// Kernel B (fused sim + band + FC): grid = 16 batches * 7 chunks of 16 t's.
// Each block computes the 16x128 sim strip it needs via MFMA (8 col-tiles,
// 2 per wave) directly into LDS, then does band extraction + FC + ReLU.
// No global sim materialization.
//   A frag: A[m=lane&15][k=quad*8+j]; B frag: B[n=lane&15][k=quad*8+j]
//   D frag: col=lane&15, row=quad*4+reg   (verified in R2 sim kernel)
// ---------------------------------------------------------------------------
__global__ __launch_bounds__(256) void simband_fc_kernel(
    const __hip_bfloat16* __restrict__ X16, const float* __restrict__ fc_w,
    const float* __restrict__ fc_b, float* __restrict__ out) {
  __shared__ __align__(16) float wlds[WIN * ODIM];   // 51712 B
  __shared__ float slds[16 * SSTR];                  // 8448 B  (16 x 128 strip)

  const int cid = blockIdx.x;
  const int b = cid / NCHUNK;
  const int t0 = (cid - b * NCHUNK) * 16;
  const int s0 = t0 - HALF;                 // strip col 0 <-> s = s0
  const int tid = threadIdx.x;
  const int lane = tid & 63, w = tid >> 6;
  const int m16 = lane & 15, quad = lane >> 4;

  // stage fc_w as float4 (overlaps with MFMA work below)
  {
    const f32x4* src = (const f32x4*)fc_w;
    f32x4* dst = (f32x4*)wlds;
    for (int i = tid; i < (WIN * ODIM) / 4; i += 256) dst[i] = src[i];
  }

  // --- MFMA: 8 col-tiles (s = s0 + 16c + n), 2 tiles per wave ---
  {
    const int c0 = 2 * w;
    const short* A = (const short*)(X16 + ((size_t)(b * TPAD + t0 + m16)) * NBINS) + quad * 8;
    // clamp out-of-range s rows into the batch (pad rows are zero; invalid
    // cols are masked in the FC loop anyway)
    int sa = s0 + c0 * 16 + m16;
    int sb = sa + 16;
    sa = min(max(sa, 0), TPAD - 1);
    sb = min(max(sb, 0), TPAD - 1);
    const short* B0 = (const short*)(X16 + ((size_t)(b * TPAD + sa)) * NBINS) + quad * 8;
    const short* B1 = (const short*)(X16 + ((size_t)(b * TPAD + sb)) * NBINS) + quad * 8;

    f32x4 acc0 = {0.f, 0.f, 0.f, 0.f};
    f32x4 acc1 = {0.f, 0.f, 0.f, 0.f};
#pragma unroll 4
    for (int k = 0; k < NBINS; k += 32) {
      s16x8 af = *(const s16x8*)(A + k);
      acc0 = __builtin_amdgcn_mfma_f32_16x16x32_bf16(af, *(const s16x8*)(B0 + k), acc0, 0, 0, 0);
      acc1 = __builtin_amdgcn_mfma_f32_16x16x32_bf16(af, *(const s16x8*)(B1 + k), acc1, 0, 0, 0);
    }
#pragma unroll
    for (int r = 0; r < 4; ++r) {
      slds[(quad * 4 + r) * SSTR + c0 * 16 + m16] = acc0[r];
      slds[(quad * 4 + r) * SSTR + (c0 + 1) * 16 + m16] = acc1[r];
    }
  }
  __syncthreads();

  // --- band + FC: thread owns d-quad g4 and rows tl0, tl0+8 ---
  const int g4 = tid & 31;        // d = 4*g4 .. 4*g4+3
  const int tl0 = tid >> 5;       // 0..7
  const int tl1 = tl0 + 8;
  const int t_a = t0 + tl0, t_b = t0 + tl1;
  // valid j range per row: s = t-50+j in [0,100)  =>  j in [50-t, 150-t)
  const int jlo0 = max(0, HALF - t_a), jhi0 = min(WIN, HALF + T_DIM - t_a);
  const int jlo1 = max(0, HALF - t_b), jhi1 = min(WIN, HALF + T_DIM - t_b);

  f32x4 acc0 = ((const f32x4*)fc_b)[g4];
  f32x4 acc1 = acc0;
#pragma unroll 4
  for (int j = 0; j < WIN; ++j) {
    f32x4 wv = *(const f32x4*)&wlds[j * ODIM + g4 * 4];
    // strip col = s - s0 = tl + j
    float b0 = (j >= jlo0 && j < jhi0) ? slds[tl0 * SSTR + tl0 + j] : 0.f;
    float b1 = (j >= jlo1 && j < jhi1) ? slds[tl1 * SSTR + tl1 + j] : 0.f;
    acc0 += wv * b0;
    acc1 += wv * b1;
  }

#pragma unroll
  for (int c = 0; c < 4; ++c) {
    acc0[c] = fmaxf(acc0[c], 0.f);
    acc1[c] = fmaxf(acc1[c], 0.f);
  }

  if (t_a < T_DIM)
    *(f32x4*)&out[(((size_t)b * T_DIM + t_a)) * ODIM + g4 * 4] = acc0;
  if (t_b < T_DIM)
    *(f32x4*)&out[(((size_t)b * T_DIM + t_b)) * ODIM + g4 * 4] = acc1;
}

extern "C" void kernel_launch(void* const* d_in, const int* in_sizes, int n_in,
                              void* d_out, int out_size, void* d_ws, size_t ws_size,
                              hipStream_t stream) {
  const int* frames = (const int*)d_in[0];     // (16,100,27,48,3) int32
  const float* fc_w = (const float*)d_in[1];   // (101,128) f32
  const float* fc_b = (const float*)d_in[2];   // (128,) f32
  float* out = (float*)d_out;                  // (16,100,128) f32

  __hip_bfloat16* X16 = (__hip_bfloat16*)d_ws; // 16*112*512 bf16 = 1.835 MB

  hist_kernel<<<B_DIM * T_DIM + B_DIM * (TPAD - T_DIM), 256, 0, stream>>>(frames, X16);
  simband_fc_kernel<<<B_DIM * NCHUNK, 256, 0, stream>>>(X16, fc_w, fc_b, out);
}